// Round 12
// baseline (118.217 us; speedup 1.0000x reference)
//
#include <hip/hip_runtime.h>
#include <hip/hip_bf16.h>

#define BATCH 8
#define SEQ   512
#define DIM   512
#define NL    64

typedef float f32x4 __attribute__((ext_vector_type(4)));
using bf16x8 = __attribute__((ext_vector_type(8))) short;   // 8 bf16 = 4 VGPRs

// f32 -> bf16 RNE (bit trick; inputs finite)
static __device__ __forceinline__ unsigned bf1(float f) {
    unsigned u = __builtin_bit_cast(unsigned, f);
    return (u + 0x7FFFu + ((u >> 16) & 1u)) >> 16;
}
static __device__ __forceinline__ unsigned bfpair(float a, float b) {
    return bf1(a) | (bf1(b) << 16);
}

// Kernel 0 — byte-identical to round 11. W f32 -> Wbf[hd][l][k] bf16.
__global__ __launch_bounds__(256) void alab_wt2(
    const float* __restrict__ W, unsigned short* __restrict__ wbf)
{
    const int tid = blockIdx.x * 256 + threadIdx.x;   // 0..16383
    const int hd  = tid >> 13;
    const int l   = (tid >> 7) & 63;
    const int kc  = (tid & 127) * 4;
    const float4 f = *(const float4*)(W + (size_t)l * (2 * DIM) + hd * DIM + kc);
    uint2 o = { bfpair(f.x, f.y), bfpair(f.z, f.w) };
    *(uint2*)(wbf + ((size_t)hd * NL + l) * DIM + kc) = o;
}

// proj v6 (MFMA) — byte-identical to round 11.
__global__ __launch_bounds__(256) void alab_proj6(
    const float* __restrict__ head, const float* __restrict__ dep,
    const unsigned short* __restrict__ wbf, const float* __restrict__ bias,
    float* __restrict__ hbuf, float* __restrict__ dbuf)
{
    __shared__ __align__(16) unsigned short A_lds[16 * 520];  // 16.25 KB
    const int bid   = blockIdx.x;
    const int hd    = bid & 1;                  // 0 = head->h, 1 = dep->d
    const int itile = (bid >> 1) & 31;
    const int b     = bid >> 6;
    const int i0    = itile * 16;

    const float* src = hd ? dep  : head;
    float*       dst = hd ? dbuf : hbuf;

    const float* arow = src + ((size_t)b * SEQ + i0) * DIM;
    #pragma unroll
    for (int u = threadIdx.x; u < 1024; u += 256) {
        const int row = u >> 6, kc = (u & 63) * 8;
        const float* p = arow + row * DIM + kc;
        const float4 f0 = *(const float4*)p;
        const float4 f1 = *(const float4*)(p + 4);
        uint4 wv = { bfpair(f0.x, f0.y), bfpair(f0.z, f0.w),
                     bfpair(f1.x, f1.y), bfpair(f1.z, f1.w) };
        *(uint4*)&A_lds[row * 520 + kc] = wv;
    }
    __syncthreads();

    const int lane = threadIdx.x & 63;
    const int w    = threadIdx.x >> 6;          // wave -> l quadrant
    const int lr   = lane & 15;                 // A: i-row / B: l-row / C: col
    const int kg   = lane >> 4;                 // k-group (8 bf16 each)

    const unsigned short* Ab = &A_lds[lr * 520 + kg * 8];
    const unsigned short* Bb = wbf + ((size_t)hd * NL + w * 16 + lr) * DIM + kg * 8;

    f32x4 acc0 = {0.f, 0.f, 0.f, 0.f}, acc1 = {0.f, 0.f, 0.f, 0.f};
    #pragma unroll
    for (int s = 0; s < 16; s += 2) {           // 2 accumulators for ILP
        const bf16x8 a0 = *(const bf16x8*)(Ab + (s + 0) * 32);
        const bf16x8 b0 = *(const bf16x8*)(Bb + (s + 0) * 32);
        const bf16x8 a1 = *(const bf16x8*)(Ab + (s + 1) * 32);
        const bf16x8 b1 = *(const bf16x8*)(Bb + (s + 1) * 32);
        acc0 = __builtin_amdgcn_mfma_f32_16x16x32_bf16(a0, b0, acc0, 0, 0, 0);
        acc1 = __builtin_amdgcn_mfma_f32_16x16x32_bf16(a1, b1, acc1, 0, 0, 0);
    }
    const f32x4 acc = acc0 + acc1;

    // C layout (m89-verified): col = lane&15 (=l), row = (lane>>4)*4 + reg (=i)
    const int l = w * 16 + lr;
    const int i = i0 + kg * 4;
    const float bb = hd ? 0.f : bias[l];        // bias folded into h
    const f32x4 r = acc + bb;
    *(f32x4*)(dst + ((size_t)b * NL + l) * SEQ + i) = r;
}

// bcast v5: identical to bcast4 except the store is NONTEMPORAL.
// This is the untried cell of the {NT,plain} x {loads,LDS} matrix.
// Theory: plain stores pay L2 write-allocate machinery (5.4 TB/s pinned
// across 5 structural variants); NT bypasses L2. With no loads in the loop
// there is nothing left that needs L2.
__global__ __launch_bounds__(256) void alab_bcast5(
    const float* __restrict__ hbuf, const float* __restrict__ dbuf,
    float* __restrict__ out)
{
    __shared__ float sh[SEQ];        // full h row for this (b,l)
    __shared__ f32x4 sd4[SEQ / 4];   // full d row
    const int t  = threadIdx.x;
    const int bl = blockIdx.x;       // b*NL + l, 0..511

    sh[t]                  = hbuf[(size_t)bl * SEQ + t];
    sh[t + 256]            = hbuf[(size_t)bl * SEQ + t + 256];
    ((float*)sd4)[t]       = dbuf[(size_t)bl * SEQ + t];
    ((float*)sd4)[t + 256] = dbuf[(size_t)bl * SEQ + t + 256];
    __syncthreads();

    const int j4 = t & 127;                     // fixed float4 column
    const int rh = t >> 7;                      // row parity (0/1)
    const f32x4 dreg = sd4[j4];                 // loop-invariant
    f32x4* ob = (f32x4*)out + (size_t)bl * SEQ * (SEQ / 4);

    #pragma unroll 8
    for (int ii = 0; ii < SEQ; ii += 2) {
        const int i = ii + rh;
        const f32x4 o = dreg + sh[i];
        __builtin_nontemporal_store(o, &ob[(size_t)i * (SEQ / 4) + j4]);
    }
}

extern "C" void kernel_launch(void* const* d_in, const int* in_sizes, int n_in,
                              void* d_out, int out_size, void* d_ws, size_t ws_size,
                              hipStream_t stream) {
    const float* head = (const float*)d_in[0];
    const float* dep  = (const float*)d_in[1];
    const float* W    = (const float*)d_in[2];
    const float* bias = (const float*)d_in[3];
    float* out = (float*)d_out;

    const size_t P = (size_t)BATCH * NL * SEQ;           // 262144 floats
    float* hbuf = (float*)d_ws;                          // 1 MiB
    float* dbuf = hbuf + P;                              // 1 MiB
    unsigned short* wbf = (unsigned short*)(dbuf + P);   // 128 KB bf16 W

    alab_wt2  <<<64,         256, 0, stream>>>(W, wbf);
    alab_proj6<<<BATCH * 64, 256, 0, stream>>>(head, dep, wbf, bias, hbuf, dbuf);
    alab_bcast5<<<BATCH * NL, 256, 0, stream>>>(hbuf, dbuf, out);
}

// Round 13
// 113.486 us; speedup vs baseline: 1.0417x; 1.0417x over previous
//
#include <hip/hip_runtime.h>
#include <hip/hip_bf16.h>

#define BATCH 8
#define SEQ   512
#define DIM   512
#define NL    64

typedef float f32x4 __attribute__((ext_vector_type(4)));
using bf16x8 = __attribute__((ext_vector_type(8))) short;   // 8 bf16 = 4 VGPRs

// f32 -> bf16 RNE (bit trick; inputs finite)
static __device__ __forceinline__ unsigned bf1(float f) {
    unsigned u = __builtin_bit_cast(unsigned, f);
    return (u + 0x7FFFu + ((u >> 16) & 1u)) >> 16;
}
static __device__ __forceinline__ unsigned bfpair(float a, float b) {
    return bf1(a) | (bf1(b) << 16);
}

// Kernel 0 — byte-identical to rounds 11/12. W f32 -> Wbf[hd][l][k] bf16.
__global__ __launch_bounds__(256) void alab_wt2(
    const float* __restrict__ W, unsigned short* __restrict__ wbf)
{
    const int tid = blockIdx.x * 256 + threadIdx.x;   // 0..16383
    const int hd  = tid >> 13;
    const int l   = (tid >> 7) & 63;
    const int kc  = (tid & 127) * 4;
    const float4 f = *(const float4*)(W + (size_t)l * (2 * DIM) + hd * DIM + kc);
    uint2 o = { bfpair(f.x, f.y), bfpair(f.z, f.w) };
    *(uint2*)(wbf + ((size_t)hd * NL + l) * DIM + kc) = o;
}

// proj v6 (MFMA) — byte-identical to rounds 11/12.
__global__ __launch_bounds__(256) void alab_proj6(
    const float* __restrict__ head, const float* __restrict__ dep,
    const unsigned short* __restrict__ wbf, const float* __restrict__ bias,
    float* __restrict__ hbuf, float* __restrict__ dbuf)
{
    __shared__ __align__(16) unsigned short A_lds[16 * 520];  // 16.25 KB
    const int bid   = blockIdx.x;
    const int hd    = bid & 1;                  // 0 = head->h, 1 = dep->d
    const int itile = (bid >> 1) & 31;
    const int b     = bid >> 6;
    const int i0    = itile * 16;

    const float* src = hd ? dep  : head;
    float*       dst = hd ? dbuf : hbuf;

    const float* arow = src + ((size_t)b * SEQ + i0) * DIM;
    #pragma unroll
    for (int u = threadIdx.x; u < 1024; u += 256) {
        const int row = u >> 6, kc = (u & 63) * 8;
        const float* p = arow + row * DIM + kc;
        const float4 f0 = *(const float4*)p;
        const float4 f1 = *(const float4*)(p + 4);
        uint4 wv = { bfpair(f0.x, f0.y), bfpair(f0.z, f0.w),
                     bfpair(f1.x, f1.y), bfpair(f1.z, f1.w) };
        *(uint4*)&A_lds[row * 520 + kc] = wv;
    }
    __syncthreads();

    const int lane = threadIdx.x & 63;
    const int w    = threadIdx.x >> 6;          // wave -> l quadrant
    const int lr   = lane & 15;                 // A: i-row / B: l-row / C: col
    const int kg   = lane >> 4;                 // k-group (8 bf16 each)

    const unsigned short* Ab = &A_lds[lr * 520 + kg * 8];
    const unsigned short* Bb = wbf + ((size_t)hd * NL + w * 16 + lr) * DIM + kg * 8;

    f32x4 acc0 = {0.f, 0.f, 0.f, 0.f}, acc1 = {0.f, 0.f, 0.f, 0.f};
    #pragma unroll
    for (int s = 0; s < 16; s += 2) {           // 2 accumulators for ILP
        const bf16x8 a0 = *(const bf16x8*)(Ab + (s + 0) * 32);
        const bf16x8 b0 = *(const bf16x8*)(Bb + (s + 0) * 32);
        const bf16x8 a1 = *(const bf16x8*)(Ab + (s + 1) * 32);
        const bf16x8 b1 = *(const bf16x8*)(Bb + (s + 1) * 32);
        acc0 = __builtin_amdgcn_mfma_f32_16x16x32_bf16(a0, b0, acc0, 0, 0, 0);
        acc1 = __builtin_amdgcn_mfma_f32_16x16x32_bf16(a1, b1, acc1, 0, 0, 0);
    }
    const f32x4 acc = acc0 + acc1;

    // C layout (m89-verified): col = lane&15 (=l), row = (lane>>4)*4 + reg (=i)
    const int l = w * 16 + lr;
    const int i = i0 + kg * 4;
    const float bb = hd ? 0.f : bias[l];        // bias folded into h
    const f32x4 r = acc + bb;
    *(f32x4*)(dst + ((size_t)b * NL + l) * SEQ + i) = r;
}

// bcast v6: SAME inner loop / LDS preload / plain stores as bcast4 (the best
// cell), but grid 512 -> 256 blocks: 1 block/CU, 4 waves/CU — matching the
// fill kernel's ~3.4-wave/CU operating point. Each block handles 2
// consecutive (b,l) tiles = one contiguous 2 MiB span. Tests the one
// untried variable: per-CU write-stream concurrency below 8 waves.
__global__ __launch_bounds__(256) void alab_bcast6(
    const float* __restrict__ hbuf, const float* __restrict__ dbuf,
    float* __restrict__ out)
{
    __shared__ float sh[SEQ];
    __shared__ f32x4 sd4[SEQ / 4];
    const int t = threadIdx.x;

    #pragma unroll
    for (int rep = 0; rep < 2; ++rep) {
        const int bl = blockIdx.x * 2 + rep;    // b*NL + l, 0..511

        if (rep) __syncthreads();               // protect LDS reuse
        sh[t]                  = hbuf[(size_t)bl * SEQ + t];
        sh[t + 256]            = hbuf[(size_t)bl * SEQ + t + 256];
        ((float*)sd4)[t]       = dbuf[(size_t)bl * SEQ + t];
        ((float*)sd4)[t + 256] = dbuf[(size_t)bl * SEQ + t + 256];
        __syncthreads();

        const int j4 = t & 127;                 // fixed float4 column
        const int rh = t >> 7;                  // row parity (0/1)
        const f32x4 dreg = sd4[j4];             // loop-invariant
        f32x4* ob = (f32x4*)out + (size_t)bl * SEQ * (SEQ / 4);

        #pragma unroll 8
        for (int ii = 0; ii < SEQ; ii += 2) {
            const int i = ii + rh;
            ob[(size_t)i * (SEQ / 4) + j4] = dreg + sh[i];
        }
    }
}

extern "C" void kernel_launch(void* const* d_in, const int* in_sizes, int n_in,
                              void* d_out, int out_size, void* d_ws, size_t ws_size,
                              hipStream_t stream) {
    const float* head = (const float*)d_in[0];
    const float* dep  = (const float*)d_in[1];
    const float* W    = (const float*)d_in[2];
    const float* bias = (const float*)d_in[3];
    float* out = (float*)d_out;

    const size_t P = (size_t)BATCH * NL * SEQ;           // 262144 floats
    float* hbuf = (float*)d_ws;                          // 1 MiB
    float* dbuf = hbuf + P;                              // 1 MiB
    unsigned short* wbf = (unsigned short*)(dbuf + P);   // 128 KB bf16 W

    alab_wt2  <<<64,          256, 0, stream>>>(W, wbf);
    alab_proj6<<<BATCH * 64,  256, 0, stream>>>(head, dep, wbf, bias, hbuf, dbuf);
    alab_bcast6<<<BATCH * NL / 2, 256, 0, stream>>>(hbuf, dbuf, out);
}

// Round 14
// 109.500 us; speedup vs baseline: 1.0796x; 1.0364x over previous
//
#include <hip/hip_runtime.h>
#include <hip/hip_bf16.h>

#define BATCH 8
#define SEQ   512
#define DIM   512
#define NL    64

typedef float f32x4 __attribute__((ext_vector_type(4)));
using bf16x8 = __attribute__((ext_vector_type(8))) short;   // 8 bf16 = 4 VGPRs

// f32 -> bf16 RNE pair-pack via compiler-native casts (m240: compiler
// handles bf16 cvt well; don't hand-write cvt_pk asm).
static __device__ __forceinline__ unsigned short bf1c(float f) {
    __hip_bfloat16 h = (__hip_bfloat16)f;
    return *reinterpret_cast<unsigned short*>(&h);
}
static __device__ __forceinline__ unsigned bfpair(float a, float b) {
    return (unsigned)bf1c(a) | ((unsigned)bf1c(b) << 16);
}

// proj v7 (MFMA, self-contained): like v6 but B-fragments come straight from
// the f32 W with in-register bf16 conversion — deletes the wt2 kernel, its
// launch gap, and the Wbf L2 round-trip. Per wave K-step: 1 ds_read_b128 (A)
// + 2 global_dwordx4 (W f32, 16 L2 lines — same TA pattern v6 had) + ~10
// cvt/pack VALU + 1 MFMA.
__global__ __launch_bounds__(256) void alab_proj7(
    const float* __restrict__ head, const float* __restrict__ dep,
    const float* __restrict__ W, const float* __restrict__ bias,
    float* __restrict__ hbuf, float* __restrict__ dbuf)
{
    __shared__ __align__(16) unsigned short A_lds[16 * 520];  // 16.25 KB
    const int bid   = blockIdx.x;
    const int hd    = bid & 1;                  // 0 = head->h, 1 = dep->d
    const int itile = (bid >> 1) & 31;
    const int b     = bid >> 6;
    const int i0    = itile * 16;

    const float* src = hd ? dep  : head;
    float*       dst = hd ? dbuf : hbuf;

    // ---- stage A: 16 rows x 512 f32 -> bf16 LDS (coalesced, 4 iters/thread)
    const float* arow = src + ((size_t)b * SEQ + i0) * DIM;
    #pragma unroll
    for (int u = threadIdx.x; u < 1024; u += 256) {
        const int row = u >> 6, kc = (u & 63) * 8;
        const float* p = arow + row * DIM + kc;
        const float4 f0 = *(const float4*)p;
        const float4 f1 = *(const float4*)(p + 4);
        uint4 wv = { bfpair(f0.x, f0.y), bfpair(f0.z, f0.w),
                     bfpair(f1.x, f1.y), bfpair(f1.z, f1.w) };
        *(uint4*)&A_lds[row * 520 + kc] = wv;
    }
    __syncthreads();

    const int lane = threadIdx.x & 63;
    const int w    = threadIdx.x >> 6;          // wave -> l quadrant
    const int lr   = lane & 15;                 // A: i-row / B: l-row / C: col
    const int kg   = lane >> 4;                 // k-group (8 bf16 each)

    const unsigned short* Ab = &A_lds[lr * 520 + kg * 8];
    // f32 W row for this lane's l, this hd half, this kg chunk
    const float* Wb = W + (size_t)(w * 16 + lr) * (2 * DIM) + hd * DIM + kg * 8;

    f32x4 acc0 = {0.f, 0.f, 0.f, 0.f}, acc1 = {0.f, 0.f, 0.f, 0.f};
    #pragma unroll
    for (int s = 0; s < 16; s += 2) {           // 2 accumulators for ILP
        const bf16x8 a0 = *(const bf16x8*)(Ab + (s + 0) * 32);
        const bf16x8 a1 = *(const bf16x8*)(Ab + (s + 1) * 32);
        const float4 w00 = *(const float4*)(Wb + (s + 0) * 32);
        const float4 w01 = *(const float4*)(Wb + (s + 0) * 32 + 4);
        const float4 w10 = *(const float4*)(Wb + (s + 1) * 32);
        const float4 w11 = *(const float4*)(Wb + (s + 1) * 32 + 4);
        union { bf16x8 v; unsigned u[4]; } b0, b1;
        b0.u[0] = bfpair(w00.x, w00.y); b0.u[1] = bfpair(w00.z, w00.w);
        b0.u[2] = bfpair(w01.x, w01.y); b0.u[3] = bfpair(w01.z, w01.w);
        b1.u[0] = bfpair(w10.x, w10.y); b1.u[1] = bfpair(w10.z, w10.w);
        b1.u[2] = bfpair(w11.x, w11.y); b1.u[3] = bfpair(w11.z, w11.w);
        acc0 = __builtin_amdgcn_mfma_f32_16x16x32_bf16(a0, b0.v, acc0, 0, 0, 0);
        acc1 = __builtin_amdgcn_mfma_f32_16x16x32_bf16(a1, b1.v, acc1, 0, 0, 0);
    }
    const f32x4 acc = acc0 + acc1;

    // C layout (m89-verified): col = lane&15 (=l), row = (lane>>4)*4 + reg (=i)
    const int l = w * 16 + lr;
    const int i = i0 + kg * 4;
    const float bb = hd ? 0.f : bias[l];        // bias folded into h
    const f32x4 r = acc + bb;
    *(f32x4*)(dst + ((size_t)b * NL + l) * SEQ + i) = r;
}

// bcast v4 — byte-identical to rounds 6/9/11 (the best of 8 variants).
__global__ __launch_bounds__(256) void alab_bcast4(
    const float* __restrict__ hbuf, const float* __restrict__ dbuf,
    float* __restrict__ out)
{
    __shared__ float sh[SEQ];        // full h row for this (b,l)
    __shared__ f32x4 sd4[SEQ / 4];   // full d row
    const int t  = threadIdx.x;
    const int bl = blockIdx.x;       // b*NL + l, 0..511

    sh[t]                  = hbuf[(size_t)bl * SEQ + t];
    sh[t + 256]            = hbuf[(size_t)bl * SEQ + t + 256];
    ((float*)sd4)[t]       = dbuf[(size_t)bl * SEQ + t];
    ((float*)sd4)[t + 256] = dbuf[(size_t)bl * SEQ + t + 256];
    __syncthreads();

    const int j4 = t & 127;                     // fixed float4 column
    const int rh = t >> 7;                      // row parity (0/1)
    const f32x4 dreg = sd4[j4];                 // loop-invariant
    f32x4* ob = (f32x4*)out + (size_t)bl * SEQ * (SEQ / 4);

    #pragma unroll 8
    for (int ii = 0; ii < SEQ; ii += 2) {
        const int i = ii + rh;
        ob[(size_t)i * (SEQ / 4) + j4] = dreg + sh[i];
    }
}

extern "C" void kernel_launch(void* const* d_in, const int* in_sizes, int n_in,
                              void* d_out, int out_size, void* d_ws, size_t ws_size,
                              hipStream_t stream) {
    const float* head = (const float*)d_in[0];
    const float* dep  = (const float*)d_in[1];
    const float* W    = (const float*)d_in[2];
    const float* bias = (const float*)d_in[3];
    float* out = (float*)d_out;

    const size_t P = (size_t)BATCH * NL * SEQ;           // 262144 floats
    float* hbuf = (float*)d_ws;                          // 1 MiB
    float* dbuf = hbuf + P;                              // 1 MiB

    alab_proj7<<<BATCH * 64, 256, 0, stream>>>(head, dep, W, bias, hbuf, dbuf);
    alab_bcast4<<<BATCH * NL, 256, 0, stream>>>(hbuf, dbuf, out);
}